// Round 15
// baseline (1159.655 us; speedup 1.0000x reference)
//
#include <hip/hip_runtime.h>
#include <math.h>

#define NB    256      // blocks; block b handles batch elements 2b and 2b+1
#define FDIM  80
#define LEN   111
#define TDEC  222
#define CFDIM 32
#define EOS   113      // eoT row stride: coprime with 32 banks
#define HLF   56       // xp time-half staging (56 + 55 = 111)

typedef float v2 __attribute__((ext_vector_type(2)));

__device__ __forceinline__ float rcpf(float x){ return __builtin_amdgcn_rcpf(x); }
__device__ __forceinline__ float sigm(float x){ return rcpf(1.0f + __expf(-x)); }
// tanh(x) = 1 - 2/(e^{2x}+1): valid for |x| < 40 (our args are < ~6)
__device__ __forceinline__ float ftanh(float x){
  float e = __expf(2.0f*x);
  return 1.0f - 2.0f*rcpf(e + 1.0f);
}

template<int CTRL, int ROW_MASK>
__device__ __forceinline__ float dpp_add(float x){
  int yi = __builtin_amdgcn_update_dpp(0, __builtin_bit_cast(int, x), CTRL, ROW_MASK, 0xf, false);
  return x + __builtin_bit_cast(float, yi);
}
__device__ __forceinline__ float wave_sum(float x){
  x = dpp_add<0x111, 0xf>(x);
  x = dpp_add<0x112, 0xf>(x);
  x = dpp_add<0x114, 0xf>(x);
  x = dpp_add<0x118, 0xf>(x);
  x = dpp_add<0x142, 0xa>(x);  // row_bcast:15
  x = dpp_add<0x143, 0xc>(x);  // row_bcast:31
  return __builtin_bit_cast(float, __builtin_amdgcn_readlane(__builtin_bit_cast(int, x), 63));
}
#define RL(x, u) __builtin_bit_cast(float, __builtin_amdgcn_readlane(__builtin_bit_cast(int, (x)), (u)))

// Two independent batch-chains per wave: chain B's instructions fill chain A's
// dependency stalls (and vice versa). Weights shared; activations duplicated.
__global__ __launch_bounds__(64, 1)
void attn_rnn_kernel(const float* __restrict__ g_in,
                     const float* __restrict__ enc_Wx, const float* __restrict__ enc_Wh, const float* __restrict__ enc_b,
                     const float* __restrict__ att_Wq, const float* __restrict__ att_bq,
                     const float* __restrict__ att_Wm, const float* __restrict__ att_bm,
                     const float* __restrict__ att_V,  const float* __restrict__ att_bv,
                     const float* __restrict__ loc_Wc, const float* __restrict__ loc_Wd,
                     const float* __restrict__ dec_Wx, const float* __restrict__ dec_Wh, const float* __restrict__ dec_b,
                     const float* __restrict__ out_W,  const float* __restrict__ out_b,
                     float* __restrict__ g_out)
{
  __shared__ float xpA[HLF*80], xpB[HLF*80];   // staged per time-half
  __shared__ float eoTA[20*EOS], eoTB[20*EOS];
  __shared__ float Wm_s[200];

  const int lane = threadIdx.x;
  const int bA   = 2*blockIdx.x, bB = bA + 1;
  const float* inpA = g_in + (size_t)bA * LEN * FDIM;
  const float* inpB = g_in + (size_t)bB * LEN * FDIM;

  for (int k = lane; k < 200; k += 64) Wm_s[k] = att_Wm[k];

  float V[10], wloc[10], bmv[10];
  #pragma unroll
  for (int a = 0; a < 10; a++){ V[a] = att_V[a]; bmv[a] = att_bm[a]; wloc[a] = 0.f; }
  for (int cf = 0; cf < CFDIM; ++cf){
    float lwc = loc_Wc[cf];
    #pragma unroll
    for (int a = 0; a < 10; a++) wloc[a] += lwc * loc_Wd[cf*10 + a];
  }
  const float bv = att_bv[0];
  const float ob = out_b[0];
  const float bq_l = att_bq[(lane < 10) ? lane : 0];
  const float outw = (lane < 20) ? out_W[lane] : 0.f;
  float SB = bv;                               // scores fold constant
  #pragma unroll
  for (int a = 0; a < 10; a++) SB += V[a];

  // Pair layout (r14): lane u<20 owns cols {u,u+20}; lane u+32 owns {u+40,u+60}.
  const int ur = lane & 31;
  const int u0 = (ur < 20) ? ur : 0;
  const int cA = (lane >= 32) ? (u0 + 40) : u0;
  const int cB = cA + 20;
  v2 whp[20];
  #pragma unroll
  for (int u = 0; u < 20; u++)
    whp[u] = (v2){ enc_Wh[u*80 + cA], enc_Wh[u*80 + cB] };

  // ================= encoder: two time-halves, dual chain =================
  float s_hA[20], s_hB[20];
  #pragma unroll
  for (int u = 0; u < 20; u++){ s_hA[u] = 0.f; s_hB[u] = 0.f; }
  float c_encA = 0.f, c_encB = 0.f;

  for (int half = 0; half < 2; ++half){
    const int t0 = half*HLF;
    const int tn = half ? (LEN - HLF) : HLF;
    __syncthreads();                           // xp WAR (+ Wm_s ready on half 0)
    // ---- xp prologue for this half (cols 0..63) ----
    {
      float wxc[80];
      #pragma unroll
      for (int i = 0; i < 80; i++) wxc[i] = enc_Wx[i*80 + lane];
      const float ebj = enc_b[lane];
      for (int tt = 0; tt < tn; tt++){
        const float* xrA = inpA + (t0+tt)*FDIM;
        const float* xrB = inpB + (t0+tt)*FDIM;
        float pA0=0.f,pA1=0.f,pA2=0.f,pA3=0.f;
        float pB0=0.f,pB1=0.f,pB2=0.f,pB3=0.f;
        #pragma unroll
        for (int i = 0; i < 80; i += 4){
          pA0 += xrA[i  ]*wxc[i  ]; pA1 += xrA[i+1]*wxc[i+1];
          pA2 += xrA[i+2]*wxc[i+2]; pA3 += xrA[i+3]*wxc[i+3];
          pB0 += xrB[i  ]*wxc[i  ]; pB1 += xrB[i+1]*wxc[i+1];
          pB2 += xrB[i+2]*wxc[i+2]; pB3 += xrB[i+3]*wxc[i+3];
        }
        xpA[tt*80 + lane] = ebj + ((pA0+pA1)+(pA2+pA3));
        xpB[tt*80 + lane] = ebj + ((pB0+pB1)+(pB2+pB3));
      }
    }
    // ---- cols 64..79 ----
    {
      const int col = 64 + (lane >> 2);
      float wxc[80];
      #pragma unroll
      for (int i = 0; i < 80; i++) wxc[i] = enc_Wx[i*80 + col];
      const float ebj = enc_b[col];
      for (int tt = (lane & 3); tt < tn; tt += 4){
        const float* xrA = inpA + (t0+tt)*FDIM;
        const float* xrB = inpB + (t0+tt)*FDIM;
        float pA0=0.f,pA1=0.f,pA2=0.f,pA3=0.f;
        float pB0=0.f,pB1=0.f,pB2=0.f,pB3=0.f;
        #pragma unroll
        for (int i = 0; i < 80; i += 4){
          pA0 += xrA[i  ]*wxc[i  ]; pA1 += xrA[i+1]*wxc[i+1];
          pA2 += xrA[i+2]*wxc[i+2]; pA3 += xrA[i+3]*wxc[i+3];
          pB0 += xrB[i  ]*wxc[i  ]; pB1 += xrB[i+1]*wxc[i+1];
          pB2 += xrB[i+2]*wxc[i+2]; pB3 += xrB[i+3]*wxc[i+3];
        }
        xpA[tt*80 + col] = ebj + ((pA0+pA1)+(pA2+pA3));
        xpB[tt*80 + col] = ebj + ((pB0+pB1)+(pB2+pB3));
      }
    }
    __syncthreads();
    // ---- encoder steps (A,B interleaved) ----
    for (int tt = 0; tt < tn; tt++){
      const int t = t0 + tt;
      v2 aA0 = (v2){ xpA[tt*80 + cA], xpA[tt*80 + cB] };
      v2 aB0 = (v2){ xpB[tt*80 + cA], xpB[tt*80 + cB] };
      v2 aA1 = (v2){0.f,0.f}, aA2 = (v2){0.f,0.f}, aA3 = (v2){0.f,0.f};
      v2 aB1 = (v2){0.f,0.f}, aB2 = (v2){0.f,0.f}, aB3 = (v2){0.f,0.f};
      #pragma unroll
      for (int u = 0; u < 20; u += 4){
        aA0 += s_hA[u  ]*whp[u  ]; aB0 += s_hB[u  ]*whp[u  ];
        aA1 += s_hA[u+1]*whp[u+1]; aB1 += s_hB[u+1]*whp[u+1];
        aA2 += s_hA[u+2]*whp[u+2]; aB2 += s_hB[u+2]*whp[u+2];
        aA3 += s_hA[u+3]*whp[u+3]; aB3 += s_hB[u+3]*whp[u+3];
      }
      v2 zA = (aA0 + aA1) + (aA2 + aA3);
      v2 zB = (aB0 + aB1) + (aB2 + aB3);
      float oxA = __shfl_xor(zA.x, 32, 64), oyA = __shfl_xor(zA.y, 32, 64);
      float oxB = __shfl_xor(zB.x, 32, 64), oyB = __shfl_xor(zB.y, 32, 64);
      float hA = 0.f, hB = 0.f;
      if (lane < 20){
        c_encA = sigm(zA.y)*c_encA + sigm(zA.x)*ftanh(oxA);
        hA     = sigm(oyA)*ftanh(c_encA);
        eoTA[lane*EOS + t] = hA;
        c_encB = sigm(zB.y)*c_encB + sigm(zB.x)*ftanh(oxB);
        hB     = sigm(oyB)*ftanh(c_encB);
        eoTB[lane*EOS + t] = hB;
      }
      #pragma unroll
      for (int u = 0; u < 20; u++){ s_hA[u] = RL(hA, u); s_hB[u] = RL(hB, u); }
    }
  }
  __syncthreads();                             // eoT ready

  // ---- per-lane eo rows + mem_proj rows -> registers (both chains) ----
  const int l1 = (lane < 47) ? lane + 64 : lane;
  float erA0[20], erA1[20], erB0[20], erB1[20];
  #pragma unroll
  for (int u = 0; u < 20; u++){
    erA0[u] = eoTA[u*EOS + lane]; erA1[u] = eoTA[u*EOS + l1];
    erB0[u] = eoTB[u*EOS + lane]; erB1[u] = eoTB[u*EOS + l1];
  }
  float mpA0[10], mpA1[10], mpB0[10], mpB1[10];
  #pragma unroll
  for (int a = 0; a < 10; a++){
    float mA0 = bmv[a], mA1 = bmv[a], mB0 = bmv[a], mB1 = bmv[a];
    #pragma unroll
    for (int u = 0; u < 20; u++){
      float w = Wm_s[u*10 + a];
      mA0 += erA0[u]*w; mA1 += erA1[u]*w;
      mB0 += erB0[u]*w; mB1 += erB1[u]*w;
    }
    mpA0[a] = mA0; mpA1[a] = mA1; mpB0[a] = mB0; mpB1[a] = mB1;
  }

  // ---- decoder weights (shared) ----
  v2 dwxp[20], dwhp[20];
  #pragma unroll
  for (int u = 0; u < 20; u++){
    dwxp[u] = (v2){ dec_Wx[u*80 + cA], dec_Wx[u*80 + cB] };
    dwhp[u] = (v2){ dec_Wh[u*80 + cA], dec_Wh[u*80 + cB] };
  }
  const v2 dbp = (v2){ dec_b[cA], dec_b[cB] };
  float wq[20];
  if (lane < 10){
    #pragma unroll
    for (int u = 0; u < 20; u++) wq[u] = att_Wq[u*10 + lane];
  }

  float s_cA[20], s_cB[20];
  #pragma unroll
  for (int u = 0; u < 20; u++){ s_cA[u] = 0.f; s_cB[u] = 0.f; s_hA[u] = 0.f; s_hB[u] = 0.f; }

  // ================= decoder: dual chain, barrier-free =================
  float apA0 = 0.f, apA1 = 0.f, apB0 = 0.f, apB1 = 0.f;
  float c_decA = 0.f, c_decB = 0.f;
  for (int t = 0; t < TDEC; t++){
    // q = c @ att_Wq + bq (query from CELL state, per reference)
    float qvA = bq_l, qvB = bq_l;
    if (lane < 10){
      float qa = 0.f, qb = 0.f, qc = 0.f, qd = 0.f;
      #pragma unroll
      for (int u = 0; u < 20; u += 2){
        qa += s_cA[u]*wq[u]; qb += s_cA[u+1]*wq[u+1];
        qc += s_cB[u]*wq[u]; qd += s_cB[u+1]*wq[u+1];
      }
      qvA += qa + qb; qvB += qc + qd;
    }
    float s_qA[10], s_qB[10];
    #pragma unroll
    for (int a = 0; a < 10; a++){ s_qA[a] = RL(qvA, a); s_qB[a] = RL(qvB, a); }

    // scores (SB fold, inline loc-tanh) — A and B interleaved
    float rA00=0.f, rA01=0.f, rA10=0.f, rA11=0.f;
    float rB00=0.f, rB01=0.f, rB10=0.f, rB11=0.f;
    #pragma unroll
    for (int a = 0; a < 10; a += 2){
      float pA0 = mpA0[a]   + s_qA[a]   + ftanh(wloc[a]*apA0);
      float pA1 = mpA1[a]   + s_qA[a]   + ftanh(wloc[a]*apA1);
      float pA2 = mpA0[a+1] + s_qA[a+1] + ftanh(wloc[a+1]*apA0);
      float pA3 = mpA1[a+1] + s_qA[a+1] + ftanh(wloc[a+1]*apA1);
      float pB0 = mpB0[a]   + s_qB[a]   + ftanh(wloc[a]*apB0);
      float pB1 = mpB1[a]   + s_qB[a]   + ftanh(wloc[a]*apB1);
      float pB2 = mpB0[a+1] + s_qB[a+1] + ftanh(wloc[a+1]*apB0);
      float pB3 = mpB1[a+1] + s_qB[a+1] + ftanh(wloc[a+1]*apB1);
      rA00 += V[a]  *rcpf(__expf(2.0f*pA0) + 1.0f);
      rA01 += V[a]  *rcpf(__expf(2.0f*pA1) + 1.0f);
      rA10 += V[a+1]*rcpf(__expf(2.0f*pA2) + 1.0f);
      rA11 += V[a+1]*rcpf(__expf(2.0f*pA3) + 1.0f);
      rB00 += V[a]  *rcpf(__expf(2.0f*pB0) + 1.0f);
      rB01 += V[a]  *rcpf(__expf(2.0f*pB1) + 1.0f);
      rB10 += V[a+1]*rcpf(__expf(2.0f*pB2) + 1.0f);
      rB11 += V[a+1]*rcpf(__expf(2.0f*pB3) + 1.0f);
    }
    float eA0 = __expf(SB - 2.0f*(rA00 + rA10));
    float eA1 = (lane < 47) ? __expf(SB - 2.0f*(rA01 + rA11)) : 0.f;
    float eB0 = __expf(SB - 2.0f*(rB00 + rB10));
    float eB1 = (lane < 47) ? __expf(SB - 2.0f*(rB01 + rB11)) : 0.f;
    float invA = rcpf(wave_sum(eA0 + eA1));
    float invB = rcpf(wave_sum(eB0 + eB1));
    apA0 = eA0*invA; apA1 = eA1*invA;
    apB0 = eB0*invB; apB1 = eB1*invB;

    // ctx reduces fused into zx accumulation (scalar ws temps, 2-way parity split)
    v2 zxA0 = (v2){0.f,0.f}, zxA1 = (v2){0.f,0.f};
    v2 zxB0 = (v2){0.f,0.f}, zxB1 = (v2){0.f,0.f};
    v2 zhA0 = dbp, zhA1 = (v2){0.f,0.f};
    v2 zhB0 = dbp, zhB1 = (v2){0.f,0.f};
    #pragma unroll
    for (int u = 0; u < 20; u += 2){
      float wA0 = wave_sum(eA0*erA0[u]   + eA1*erA1[u]);
      float wB0 = wave_sum(eB0*erB0[u]   + eB1*erB1[u]);
      float wA1 = wave_sum(eA0*erA0[u+1] + eA1*erA1[u+1]);
      float wB1 = wave_sum(eB0*erB0[u+1] + eB1*erB1[u+1]);
      zxA0 += wA0*dwxp[u]; zxA1 += wA1*dwxp[u+1];
      zxB0 += wB0*dwxp[u]; zxB1 += wB1*dwxp[u+1];
      zhA0 += s_hA[u]*dwhp[u]; zhA1 += s_hA[u+1]*dwhp[u+1];
      zhB0 += s_hB[u]*dwhp[u]; zhB1 += s_hB[u+1]*dwhp[u+1];
    }
    v2 zA, zB;
    {
      v2 hA2 = zhA0 + zhA1, xA2 = zxA0 + zxA1;
      v2 hB2 = zhB0 + zhB1, xB2 = zxB0 + zxB1;
      zA.x = hA2.x + xA2.x*invA; zA.y = hA2.y + xA2.y*invA;
      zB.x = hB2.x + xB2.x*invB; zB.y = hB2.y + xB2.y*invB;
    }
    float oxA = __shfl_xor(zA.x, 32, 64), oyA = __shfl_xor(zA.y, 32, 64);
    float oxB = __shfl_xor(zB.x, 32, 64), oyB = __shfl_xor(zB.y, 32, 64);

    float hA = 0.f, hB = 0.f;
    if (lane < 20){
      c_decA = sigm(zA.y)*c_decA + sigm(zA.x)*ftanh(oxA);
      hA     = sigm(oyA)*ftanh(c_decA);
      c_decB = sigm(zB.y)*c_decB + sigm(zB.x)*ftanh(oxB);
      hB     = sigm(oyB)*ftanh(c_decB);
    }

    // state broadcast (feeds next step's q and zh)
    #pragma unroll
    for (int u = 0; u < 20; u++){
      s_cA[u] = RL(c_decA, u); s_hA[u] = RL(hA, u);
      s_cB[u] = RL(c_decB, u); s_hB[u] = RL(hB, u);
    }

    // y outputs (dead-end)
    float pvA = wave_sum(hA*outw);
    float pvB = wave_sum(hB*outw);
    if (lane == 0){
      g_out[(size_t)bA*TDEC + t] = ftanh(pvA + ob);
      g_out[(size_t)bB*TDEC + t] = ftanh(pvB + ob);
    }
  }
}

extern "C" void kernel_launch(void* const* d_in, const int* in_sizes, int n_in,
                              void* d_out, int out_size, void* d_ws, size_t ws_size,
                              hipStream_t stream) {
  const float* g_in   = (const float*)d_in[0];
  const float* enc_Wx = (const float*)d_in[1];
  const float* enc_Wh = (const float*)d_in[2];
  const float* enc_b  = (const float*)d_in[3];
  const float* att_Wq = (const float*)d_in[4];
  const float* att_bq = (const float*)d_in[5];
  const float* att_Wm = (const float*)d_in[6];
  const float* att_bm = (const float*)d_in[7];
  const float* att_V  = (const float*)d_in[8];
  const float* att_bv = (const float*)d_in[9];
  const float* loc_Wc = (const float*)d_in[10];
  const float* loc_Wd = (const float*)d_in[11];
  const float* dec_Wx = (const float*)d_in[12];
  const float* dec_Wh = (const float*)d_in[13];
  const float* dec_b  = (const float*)d_in[14];
  const float* out_W  = (const float*)d_in[15];
  const float* out_b  = (const float*)d_in[16];
  float* g_out = (float*)d_out;

  hipLaunchKernelGGL(attn_rnn_kernel, dim3(NB), dim3(64), 0, stream,
                     g_in, enc_Wx, enc_Wh, enc_b, att_Wq, att_bq, att_Wm, att_bm,
                     att_V, att_bv, loc_Wc, loc_Wd, dec_Wx, dec_Wh, dec_b,
                     out_W, out_b, g_out);
}

// Round 17
// 567.901 us; speedup vs baseline: 2.0420x; 2.0420x over previous
//
#include <hip/hip_runtime.h>
#include <math.h>

#define NB    512
#define FDIM  80
#define LEN   111
#define TDEC  222
#define CFDIM 32
#define EOS   113   // eoT row stride: coprime with 32 banks -> conflict-free

typedef float v2 __attribute__((ext_vector_type(2)));

__device__ __forceinline__ float rcpf(float x){ return __builtin_amdgcn_rcpf(x); }
__device__ __forceinline__ float sigm(float x){ return rcpf(1.0f + __expf(-x)); }
// tanh(x) = 1 - 2/(e^{2x}+1): valid for |x| < 40 (our args are < ~6)
__device__ __forceinline__ float ftanh(float x){
  float e = __expf(2.0f*x);
  return 1.0f - 2.0f*rcpf(e + 1.0f);
}

template<int CTRL, int ROW_MASK>
__device__ __forceinline__ float dpp_add(float x){
  int yi = __builtin_amdgcn_update_dpp(0, __builtin_bit_cast(int, x), CTRL, ROW_MASK, 0xf, false);
  return x + __builtin_bit_cast(float, yi);
}
__device__ __forceinline__ float wave_sum(float x){
  x = dpp_add<0x111, 0xf>(x);
  x = dpp_add<0x112, 0xf>(x);
  x = dpp_add<0x114, 0xf>(x);
  x = dpp_add<0x118, 0xf>(x);
  x = dpp_add<0x142, 0xa>(x);  // row_bcast:15
  x = dpp_add<0x143, 0xc>(x);  // row_bcast:31
  return __builtin_bit_cast(float, __builtin_amdgcn_readlane(__builtin_bit_cast(int, x), 63));
}
#define RL(x, u) __builtin_bit_cast(float, __builtin_amdgcn_readlane(__builtin_bit_cast(int, (x)), (u)))

__global__ __launch_bounds__(64, 1)
void attn_rnn_kernel(const float* __restrict__ g_in,
                     const float* __restrict__ enc_Wx, const float* __restrict__ enc_Wh, const float* __restrict__ enc_b,
                     const float* __restrict__ att_Wq, const float* __restrict__ att_bq,
                     const float* __restrict__ att_Wm, const float* __restrict__ att_bm,
                     const float* __restrict__ att_V,  const float* __restrict__ att_bv,
                     const float* __restrict__ loc_Wc, const float* __restrict__ loc_Wd,
                     const float* __restrict__ dec_Wx, const float* __restrict__ dec_Wh, const float* __restrict__ dec_b,
                     const float* __restrict__ out_W,  const float* __restrict__ out_b,
                     float* __restrict__ g_out)
{
  __shared__ float xp[LEN*80];
  __shared__ float eoT[20*EOS];
  __shared__ float Wm_s[200];

  const int lane = threadIdx.x;
  const int b    = blockIdx.x;
  const float* inp = g_in + (size_t)b * LEN * FDIM;

  for (int k = lane; k < 200; k += 64) Wm_s[k] = att_Wm[k];

  float V[10], wloc[10], bmv[10];
  #pragma unroll
  for (int a = 0; a < 10; a++){ V[a] = att_V[a]; bmv[a] = att_bm[a]; wloc[a] = 0.f; }
  for (int cf = 0; cf < CFDIM; ++cf){
    float lwc = loc_Wc[cf];
    #pragma unroll
    for (int a = 0; a < 10; a++) wloc[a] += lwc * loc_Wd[cf*10 + a];
  }
  const float bv = att_bv[0];
  const float ob = out_b[0];
  const float bq_l = att_bq[(lane < 10) ? lane : 0];
  const float outw = (lane < 20) ? out_W[lane] : 0.f;
  // scores fold: sum_a V_a*tanh(pre_a) = SB - 2*sum_a V_a*rcp(e^{2pre_a}+1)
  float SB = bv;
  #pragma unroll
  for (int a = 0; a < 10; a++) SB += V[a];

  // ---- xp prologue: xp[t][j] = x[t].Wx[:,j] + b[j] ----
  {
    float wxc[80];
    #pragma unroll
    for (int i = 0; i < 80; i++) wxc[i] = enc_Wx[i*80 + lane];
    const float ebj = enc_b[lane];
    for (int t = 0; t < LEN; t++){
      const float* xr = inp + t*FDIM;
      float a0=0.f,a1=0.f,a2=0.f,a3=0.f;
      #pragma unroll
      for (int i = 0; i < 80; i += 4){
        a0 += xr[i  ]*wxc[i  ]; a1 += xr[i+1]*wxc[i+1];
        a2 += xr[i+2]*wxc[i+2]; a3 += xr[i+3]*wxc[i+3];
      }
      xp[t*80 + lane] = ebj + ((a0+a1)+(a2+a3));
    }
  }
  {
    const int col = 64 + (lane >> 2);
    float wxc[80];
    #pragma unroll
    for (int i = 0; i < 80; i++) wxc[i] = enc_Wx[i*80 + col];
    const float ebj = enc_b[col];
    for (int t = (lane & 3); t < LEN; t += 4){
      const float* xr = inp + t*FDIM;
      float a0=0.f,a1=0.f,a2=0.f,a3=0.f;
      #pragma unroll
      for (int i = 0; i < 80; i += 4){
        a0 += xr[i  ]*wxc[i  ]; a1 += xr[i+1]*wxc[i+1];
        a2 += xr[i+2]*wxc[i+2]; a3 += xr[i+3]*wxc[i+3];
      }
      xp[t*80 + col] = ebj + ((a0+a1)+(a2+a3));
    }
  }

  // Pair layout: lane u (<20) owns cols {u, u+20} = {zi,zf};
  //              lane u+32     owns cols {u+40, u+60} = {zg,zo}.
  // Cross-lane handoff is a half-wave swap (shfl_xor 32).
  const int ur = lane & 31;
  const int u0 = (ur < 20) ? ur : 0;       // clamped for inactive lanes
  const int cA = (lane >= 32) ? (u0 + 40) : u0;
  const int cB = cA + 20;
  v2 whp[20];
  #pragma unroll
  for (int u = 0; u < 20; u++)
    whp[u] = (v2){ enc_Wh[u*80 + cA], enc_Wh[u*80 + cB] };
  __syncthreads();                         // [barrier 1/2] xp + Wm_s ready

  // ================= encoder: barrier-free =================
  float s_h[20];
  #pragma unroll
  for (int u = 0; u < 20; u++) s_h[u] = 0.f;
  float c_enc = 0.f;
  for (int t = 0; t < LEN; t++){
    v2 ac0 = (v2){ xp[t*80 + cA], xp[t*80 + cB] };
    v2 ac1 = (v2){0.f,0.f}, ac2 = (v2){0.f,0.f}, ac3 = (v2){0.f,0.f};
    #pragma unroll
    for (int u = 0; u < 20; u += 4){
      ac0 += s_h[u  ]*whp[u  ];
      ac1 += s_h[u+1]*whp[u+1];
      ac2 += s_h[u+2]*whp[u+2];
      ac3 += s_h[u+3]*whp[u+3];
    }
    v2 zp = (ac0 + ac1) + (ac2 + ac3);     // {zi,zf} lo-half / {zg,zo} hi-half
    float ox = __shfl_xor(zp.x, 32, 64);   // lane u gets zg
    float oy = __shfl_xor(zp.y, 32, 64);   // lane u gets zo
    float hval = 0.f;
    if (lane < 20){
      c_enc = sigm(zp.y)*c_enc + sigm(zp.x)*ftanh(ox);
      hval  = sigm(oy)*ftanh(c_enc);
      eoT[lane*EOS + t] = hval;
    }
    #pragma unroll
    for (int u = 0; u < 20; u++) s_h[u] = RL(hval, u);
  }
  __syncthreads();                         // [barrier 2/2] eoT ready

  // ---- per-lane eo rows + mem_proj rows -> registers ----
  const int l1 = (lane < 47) ? lane + 64 : lane;
  float er0[20], er1[20];
  #pragma unroll
  for (int u = 0; u < 20; u++){ er0[u] = eoT[u*EOS + lane]; er1[u] = eoT[u*EOS + l1]; }
  float mp0[10], mp1[10];
  #pragma unroll
  for (int a = 0; a < 10; a++){
    float m0 = bmv[a], m1 = bmv[a];
    #pragma unroll
    for (int u = 0; u < 20; u++){ m0 += er0[u]*Wm_s[u*10 + a]; m1 += er1[u]*Wm_s[u*10 + a]; }
    mp0[a] = m0; mp1[a] = m1;
  }

  // ---- decoder weights (pair layout) ----
  v2 dwxp[20], dwhp[20];
  #pragma unroll
  for (int u = 0; u < 20; u++){
    dwxp[u] = (v2){ dec_Wx[u*80 + cA], dec_Wx[u*80 + cB] };
    dwhp[u] = (v2){ dec_Wh[u*80 + cA], dec_Wh[u*80 + cB] };
  }
  const v2 dbp = (v2){ dec_b[cA], dec_b[cB] };
  float wq[20];
  if (lane < 10){
    #pragma unroll
    for (int u = 0; u < 20; u++) wq[u] = att_Wq[u*10 + lane];
  }

  float s_c[20];
  #pragma unroll
  for (int u = 0; u < 20; u++){ s_c[u] = 0.f; s_h[u] = 0.f; }

  // ================= decoder: barrier-free =================
  float ap0 = 0.f, ap1 = 0.f, c_dec = 0.f;
  for (int t = 0; t < TDEC; t++){
    // q = c @ att_Wq + bq (query from CELL state, per reference)
    float qv = bq_l;
    if (lane < 10){
      float qa = 0.f, qb = 0.f;
      #pragma unroll
      for (int u = 0; u < 20; u += 2){ qa += s_c[u]*wq[u]; qb += s_c[u+1]*wq[u+1]; }
      qv += qa + qb;
    }
    float s_q[10];
    #pragma unroll
    for (int a = 0; a < 10; a++) s_q[a] = RL(qv, a);

    // scores: sc = SB - 2*sum_a V_a * rcp(exp(2*pre_a)+1)   (inline loc-tanh)
    float r00 = 0.f, r01 = 0.f, r10 = 0.f, r11 = 0.f;
    #pragma unroll
    for (int a = 0; a < 10; a += 2){
      float pre0 = mp0[a]   + s_q[a]   + ftanh(wloc[a]*ap0);
      float pre1 = mp1[a]   + s_q[a]   + ftanh(wloc[a]*ap1);
      float pr20 = mp0[a+1] + s_q[a+1] + ftanh(wloc[a+1]*ap0);
      float pr21 = mp1[a+1] + s_q[a+1] + ftanh(wloc[a+1]*ap1);
      r00 += V[a]  *rcpf(__expf(2.0f*pre0) + 1.0f);
      r01 += V[a]  *rcpf(__expf(2.0f*pre1) + 1.0f);
      r10 += V[a+1]*rcpf(__expf(2.0f*pr20) + 1.0f);
      r11 += V[a+1]*rcpf(__expf(2.0f*pr21) + 1.0f);
    }
    // |sc| <= |bv|+sum|V| (~2): exp cannot overflow -> no max subtraction
    float e0 = __expf(SB - 2.0f*(r00 + r10));
    float e1 = (lane < 47) ? __expf(SB - 2.0f*(r01 + r11)) : 0.f;
    float inv = rcpf(wave_sum(e0 + e1));
    ap0 = e0*inv; ap1 = e1*inv;

    // ctx raw reduces: ws[u] MUST be wave-uniform BEFORE multiplying by the
    // lane-varying dwxp columns (r16's fusion was mathematically invalid).
    float ws[20];
    #pragma unroll
    for (int u = 0; u < 20; u++) ws[u] = wave_sum(e0*er0[u] + e1*er1[u]);

    // z pair = ctx@Wx + h@Wh + b: packed v2, 2-way split chains
    v2 zx0 = (v2){0.f,0.f}, zx1 = (v2){0.f,0.f};
    v2 zh0 = dbp,            zh1 = (v2){0.f,0.f};
    #pragma unroll
    for (int u = 0; u < 20; u += 2){
      zx0 += ws[u]   *dwxp[u];
      zx1 += ws[u+1] *dwxp[u+1];
      zh0 += s_h[u]  *dwhp[u];
      zh1 += s_h[u+1]*dwhp[u+1];
    }
    v2 zzh = zh0 + zh1;
    v2 zzx = zx0 + zx1;
    v2 zp;
    zp.x = zzh.x + zzx.x*inv;
    zp.y = zzh.y + zzx.y*inv;
    float ox = __shfl_xor(zp.x, 32, 64);   // zg for lanes<20
    float oy = __shfl_xor(zp.y, 32, 64);   // zo for lanes<20

    float hval = 0.f;
    if (lane < 20){
      c_dec = sigm(zp.y)*c_dec + sigm(zp.x)*ftanh(ox);
      hval  = sigm(oy)*ftanh(c_dec);
    }

    // state broadcast (feeds next step's q and zh)
    #pragma unroll
    for (int u = 0; u < 20; u++){ s_c[u] = RL(c_dec, u); s_h[u] = RL(hval, u); }

    // y output (dead-end, drains under next step's issue)
    float pv = wave_sum(hval*outw);
    if (lane == 0) g_out[(size_t)b*TDEC + t] = ftanh(pv + ob);
  }
}

extern "C" void kernel_launch(void* const* d_in, const int* in_sizes, int n_in,
                              void* d_out, int out_size, void* d_ws, size_t ws_size,
                              hipStream_t stream) {
  const float* g_in   = (const float*)d_in[0];
  const float* enc_Wx = (const float*)d_in[1];
  const float* enc_Wh = (const float*)d_in[2];
  const float* enc_b  = (const float*)d_in[3];
  const float* att_Wq = (const float*)d_in[4];
  const float* att_bq = (const float*)d_in[5];
  const float* att_Wm = (const float*)d_in[6];
  const float* att_bm = (const float*)d_in[7];
  const float* att_V  = (const float*)d_in[8];
  const float* att_bv = (const float*)d_in[9];
  const float* loc_Wc = (const float*)d_in[10];
  const float* loc_Wd = (const float*)d_in[11];
  const float* dec_Wx = (const float*)d_in[12];
  const float* dec_Wh = (const float*)d_in[13];
  const float* dec_b  = (const float*)d_in[14];
  const float* out_W  = (const float*)d_in[15];
  const float* out_b  = (const float*)d_in[16];
  float* g_out = (float*)d_out;

  hipLaunchKernelGGL(attn_rnn_kernel, dim3(NB), dim3(64), 0, stream,
                     g_in, enc_Wx, enc_Wh, enc_b, att_Wq, att_bq, att_Wm, att_bm,
                     att_V, att_bv, loc_Wc, loc_Wd, dec_Wx, dec_Wh, dec_b,
                     out_W, out_b, g_out);
}